// Round 12
// baseline (146.855 us; speedup 1.0000x reference)
//
#include <hip/hip_runtime.h>
#include <hip/hip_bf16.h>

#define NCLS   100000
#define FEAT   192
#define F4     48
#define TILE   32
#define NT2    3125        // NCLS/TILE exact

// workspace layout (float offsets)
#define XN_OFF   0
#define CM_OFF   6144
#define SM_OFF   6176
#define TH_OFF   6208
#define MM_OFF   6240
#define RG_OFF   6272
#define LV_OFF   6304
#define TGT_OFF  6336
#define CMAT_OFF 7360
#define XNH_OFF  8384      // 6144 ushort (bf16 hi of xn) = 3072 float slots
#define XNL_OFF  11456     // 6144 ushort (bf16 lo)
#define PART_OFF 14528

#define L2E30 43.2808512266689f
#define LN2   0.69314718055994531f

typedef __attribute__((ext_vector_type(8))) short bf16x8;
typedef __attribute__((ext_vector_type(4))) float f32x4;

__device__ __forceinline__ float dot4(float4 a, float4 b){
  return fmaf(a.x,b.x, fmaf(a.y,b.y, fmaf(a.z,b.z, a.w*b.w)));
}
__device__ __forceinline__ unsigned short bf_bits(__hip_bfloat16 h){
  return *reinterpret_cast<unsigned short*>(&h);
}
__device__ __forceinline__ float bf_up(short s){
  return __int_as_float(((int)(unsigned short)s) << 16);
}

// ---------------- K1: prep (params, lv, xn -> bf16 hi/lo split) ----------------
__global__ __launch_bounds__(256) void k1_prep(const float* __restrict__ pe,
                                               const int* __restrict__ gt,
                                               float* __restrict__ ws)
{
  __shared__ float4 PE4[1536];
  __shared__ float INVN[32];
  const int tid = threadIdx.x;
  const float4* pe4 = (const float4*)pe;
  for (int i = tid; i < 1536; i += 256) PE4[i] = pe4[i];
  __syncthreads();

  const int m   = tid >> 3;
  const int sub = tid & 7;
  float ssq = 0.f;
  for (int j = 0; j < 6; ++j){ float4 v = PE4[m*F4 + sub + 8*j]; ssq += dot4(v,v); }
  ssq += __shfl_xor(ssq,1); ssq += __shfl_xor(ssq,2); ssq += __shfl_xor(ssq,4);
  float nrm = sqrtf(ssq);
  if (sub == 0){
    INVN[m] = 1.f / fmaxf(nrm, 1e-12f);
    float nc = fminf(fmaxf(nrm, 10.f), 110.f);
    float mi = fmaf(0.01f, nc, 100.f/nc);
    const float pi = 3.14159265358979323846f;
    ws[CM_OFF+m] = cosf(mi);
    ws[SM_OFF+m] = sinf(mi);
    ws[TH_OFF+m] = cosf(pi - mi);
    ws[MM_OFF+m] = sinf(pi - mi)*mi;
    float dr = nc - 60.f;
    ws[RG_OFF+m] = 0.07f*dr*dr;              // GAMMA*LMBDA*0.01 = 0.07
  }
  if (tid < 32) ws[LV_OFF+tid] = (float)gt[tid];
  __syncthreads();

  unsigned short* xh = (unsigned short*)(ws + XNH_OFF);
  unsigned short* xl = (unsigned short*)(ws + XNL_OFF);
  for (int i = tid; i < 6144; i += 256){
    float v = ((float*)PE4)[i] * INVN[i/FEAT];
    ws[XN_OFF+i] = v;
    __hip_bfloat16 hb = __float2bfloat16(v);
    float hf = __bfloat162float(hb);
    __hip_bfloat16 lb = __float2bfloat16(v - hf);
    xh[i] = bf_bits(hb);
    xl[i] = bf_bits(lb);
  }
}

// ---------------- K2: MFMA split-bf16 GEMM + transform + online MAX (r11) ----------------
__global__ __launch_bounds__(256, 4) void k2_main(const float* __restrict__ wgt,
                                                  const float* __restrict__ wsr,
                                                  const int* __restrict__ gt,
                                                  float* __restrict__ part,
                                                  float* __restrict__ wsw,
                                                  int nb)
{
  __shared__ __align__(16) short WH[TILE*FEAT];   // 12KB, swizzled bf16-hi
  __shared__ __align__(16) short WL[TILE*FEAT];   // 12KB, swizzled bf16-lo
  __shared__ float4 OBS[TILE*8];                  // 4KB
  __shared__ float4 OSS[TILE*8];                  // 4KB
  __shared__ float  NRM[TILE];
  __shared__ float4 PRM[32];                      // {cm, sm, th, mm} per m

  const int tid  = threadIdx.x;
  const int lane = tid & 63;
  const int wv   = tid >> 6;
  const int clsg = wv & 1;          // cls 16-group
  const int mh   = wv >> 1;         // m half
  const float4* gw4 = (const float4*)wgt;

  if (tid < 32)
    PRM[tid] = make_float4(wsr[CM_OFF+tid], wsr[SM_OFF+tid],
                           wsr[TH_OFF+tid], wsr[MM_OFF+tid]);

  const unsigned short* xh = (const unsigned short*)(wsr + XNH_OFF);
  const unsigned short* xl = (const unsigned short*)(wsr + XNL_OFF);
  const int arow = mh*16 + (lane & 15);     // m row of A-frag
  const int acol = (lane >> 4) * 8;         // k sub-offset of A-frag
  const int bcls = clsg*16 + (lane & 15);   // cls column of B-frag
  const int bxor = (bcls & 7) << 4;

  const int s_acc = tid & 31;
  const int mgr   = tid >> 5;
  const int gt_s  = gt[s_acc];
  const float lvs = (float)gt_s;
  float mx[4];
#pragma unroll
  for (int qi = 0; qi < 4; ++qi) mx[qi] = -1e30f;

  for (int t = blockIdx.x; t < NT2; t += nb){
    const int c0 = t*TILE;
#pragma unroll
    for (int r = 0; r < 6; ++r){
      int f = r*256 + tid;
      float4 w4 = gw4[(long)t*1536 + f];
      int cls = f / F4;
      int k4  = f - cls*F4;
      float vals[4] = { w4.x, w4.y, w4.z, w4.w };
      unsigned short hb4[4], lb4[4];
#pragma unroll
      for (int e = 0; e < 4; ++e){
        __hip_bfloat16 hb = __float2bfloat16(vals[e]);
        float hf = __bfloat162float(hb);
        __hip_bfloat16 lb = __float2bfloat16(vals[e] - hf);
        hb4[e] = bf_bits(hb); lb4[e] = bf_bits(lb);
      }
      int phys = (cls*384 + k4*8) ^ ((cls & 7) << 4);
      *(ushort4*)((char*)WH + phys) = make_ushort4(hb4[0],hb4[1],hb4[2],hb4[3]);
      *(ushort4*)((char*)WL + phys) = make_ushort4(lb4[0],lb4[1],lb4[2],lb4[3]);
    }
    __syncthreads();                        // barC: tile staged
    {
      int cls = tid >> 3, seg = tid & 7;
      float nsq = 0.f;
#pragma unroll
      for (int j = 0; j < 3; ++j){
        int phys = (cls*384 + seg*48 + j*16) ^ ((cls & 7) << 4);
        bf16x8 hh = *(const bf16x8*)((char*)WH + phys);
        bf16x8 ll = *(const bf16x8*)((char*)WL + phys);
#pragma unroll
        for (int e = 0; e < 8; ++e){
          float wv_ = bf_up(hh[e]) + bf_up(ll[e]);
          nsq = fmaf(wv_, wv_, nsq);
        }
      }
      nsq += __shfl_xor(nsq,1); nsq += __shfl_xor(nsq,2); nsq += __shfl_xor(nsq,4);
      if (seg == 0) NRM[cls] = rsqrtf(fmaxf(nsq, 1e-24f));
    }
    f32x4 acc = {0.f, 0.f, 0.f, 0.f};
#pragma unroll
    for (int ks = 0; ks < 6; ++ks){
      int boff = (bcls*384 + ks*64 + (lane>>4)*16) ^ bxor;
      bf16x8 bh = *(const bf16x8*)((char*)WH + boff);
      bf16x8 bl = *(const bf16x8*)((char*)WL + boff);
      int aoff = arow*FEAT + ks*32 + acol;
      bf16x8 ah = *(const bf16x8*)(xh + aoff);
      bf16x8 al = *(const bf16x8*)(xl + aoff);
      acc = __builtin_amdgcn_mfma_f32_16x16x32_bf16(ah, bh, acc, 0, 0, 0);
      acc = __builtin_amdgcn_mfma_f32_16x16x32_bf16(al, bh, acc, 0, 0, 0);
      acc = __builtin_amdgcn_mfma_f32_16x16x32_bf16(ah, bl, acc, 0, 0, 0);
    }
    __syncthreads();                        // barA: MFMA done, NRM visible
    {
      float invn = NRM[bcls];
      float ob[4], os[4];
#pragma unroll
      for (int r = 0; r < 4; ++r){
        float c = acc[r] * invn;
        float4 pr = PRM[mh*16 + (lane>>4)*4 + r];
        float sine = sqrtf(fminf(fmaxf(1.f - c*c, 0.f), 1.f));
        float phi = c*pr.x - sine*pr.y;
        phi = (c > pr.z) ? phi : (c - pr.w);
        ob[r] = L2E30 * c;
        os[r] = L2E30 * (phi - c);
      }
      int mgw = mh*4 + (lane>>4);
      int slot = bcls*8 + (mgw ^ (bcls & 7));
      OBS[slot] = make_float4(ob[0],ob[1],ob[2],ob[3]);
      OSS[slot] = make_float4(os[0],os[1],os[2],os[3]);
    }
    __syncthreads();                        // barB: OBS/OSS visible
    {
      int rel = gt_s - c0;
      if ((unsigned)rel < (unsigned)TILE){
        int slot = rel*8 + (mgr ^ (rel & 7));
        float4 ob = OBS[slot];
        float4 os = OSS[slot];
        wsw[TGT_OFF + s_acc*32 + 4*mgr + 0] = fmaf(lvs, os.x, ob.x);
        wsw[TGT_OFF + s_acc*32 + 4*mgr + 1] = fmaf(lvs, os.y, ob.y);
        wsw[TGT_OFF + s_acc*32 + 4*mgr + 2] = fmaf(lvs, os.z, ob.z);
        wsw[TGT_OFF + s_acc*32 + 4*mgr + 3] = fmaf(lvs, os.w, ob.w);
      }
    }
#pragma unroll 8
    for (int ci = 0; ci < TILE; ++ci){
      int slot = ci*8 + (mgr ^ (ci & 7));
      float4 ob = OBS[slot];
      float4 os = OSS[slot];
      mx[0] = fmaxf(mx[0], fmaf(lvs, os.x, ob.x));
      mx[1] = fmaxf(mx[1], fmaf(lvs, os.y, ob.y));
      mx[2] = fmaxf(mx[2], fmaf(lvs, os.z, ob.z));
      mx[3] = fmaxf(mx[3], fmaf(lvs, os.w, ob.w));
    }
  }
#pragma unroll
  for (int qi = 0; qi < 4; ++qi){
    int pp = s_acc*32 + 4*mgr + qi;
    part[(long)pp*nb + blockIdx.x] = mx[qi];
  }
}

// ---------------- K3: combine partial maxes -> cost matrix ----------------
__global__ __launch_bounds__(64) void k3_reduce(const float* part, float* ws, int nb)
{
  const int p = blockIdx.x;
  const int l = threadIdx.x;
  float M = -1e30f;
  for (int base = l; base < nb; base += 64)
    M = fmaxf(M, part[(long)p*nb + base]);
  for (int k = 1; k < 64; k <<= 1)
    M = fmaxf(M, __shfl_xor(M, k));
  if (l == 0)
    ws[CMAT_OFF + p] = LN2*(M - ws[TGT_OFF + p]) + ws[RG_OFF + (p & 31)];
}

// ---------------- K4: JV with augmenting-row-reduction (LAPJV) + SAP ----------------
__device__ __forceinline__ float wave_min32(float x){
  float r = x;
#define DPPSTEP(ctrl) { int t_ = __builtin_amdgcn_update_dpp(__float_as_int(r), __float_as_int(r), (ctrl), 0xf, 0xf, false); r = fminf(r, __int_as_float(t_)); }
  DPPSTEP(0x111)
  DPPSTEP(0x112)
  DPPSTEP(0x114)
  DPPSTEP(0x118)
  DPPSTEP(0x142)
#undef DPPSTEP
  return __int_as_float(__builtin_amdgcn_readlane(__float_as_int(r), 31));
}

__global__ __launch_bounds__(64) void k4_final(const float* __restrict__ psin,
                                               const float* __restrict__ wsr,
                                               float* __restrict__ out)
{
  __shared__ float CL[1024];
  __shared__ float U[32];
  const int l = threadIdx.x;
  const int lc = l & 31;
  for (int i = l; i < 1024; i += 64) CL[i] = wsr[CMAT_OFF + i];
  __syncthreads();

  // --- row mins U[i]
  for (int i = 0; i < 32; ++i){
    float val = (l < 32) ? CL[i*32 + lc] : 1e30f;
    float mn = wave_min32(val);
    if (l == 0) U[i] = mn;
  }
  __syncthreads();
  // --- col mins of reduced cost: v[j] = min_i (C[i][j] - U[i])
  float v = 1e30f;
#pragma unroll 8
  for (int i = 0; i < 32; ++i) v = fminf(v, CL[i*32 + lc] - U[i]);
  // --- greedy zero assignment (rc==0 bitwise at argmin)
  int p = 0;                 // row+1 assigned to this lane's column (0 = free)
  float uu = 0.f;            // u[p[j]] (tight: C - uu - v == 0 on assigned)
  unsigned freemask = 0xffffffffu;
  for (int i = 0; i < 32; ++i){
    float rc = CL[i*32 + lc] - U[i] - v;
    bool z = (l < 32) && (p == 0) && (rc == 0.0f);
    unsigned long long b = __ballot(z);
    if (b){
      int j = __builtin_ctzll(b);
      if (l == j){ p = i + 1; uu = U[i]; }
      freemask &= ~(1u << i);
    }
  }
  // --- ARR: LAPJV augmenting row reduction, 2 passes.
  // Invariants kept: v only decreases (U stays feasible); assigned pairs tight
  // (uu = C - v_new = row-min reduced cost). Guard dumps leftovers to SAP.
  for (int pass = 0; pass < 2; ++pass){
    unsigned cur = freemask; freemask = 0;
    int guard = 0;
    while (cur && guard < 96){
      int r = __builtin_ctz(cur); cur &= cur - 1;
      for (;;){
        if (++guard >= 96){ freemask |= (1u << r); break; }
        float cst = (l < 32) ? CL[r*32 + lc] : 1e30f;
        float rc  = (l < 32) ? (cst - v) : 1e30f;
        float m1 = wave_min32(rc);
        unsigned long long b1 = __ballot(rc == m1);
        int j1 = __builtin_ctzll(b1);
        float rc2 = (l == j1) ? 1e30f : rc;
        float m2 = wave_min32(rc2);
        int i0 = __builtin_amdgcn_readlane(p, j1);
        if (m1 < m2){
          if (l == j1) v -= (m2 - m1);
        } else if (i0 > 0){
          unsigned long long b2 = __ballot(rc2 == m2);
          j1 = __builtin_ctzll(b2);
          i0 = __builtin_amdgcn_readlane(p, j1);
        }
        if (l == j1){ p = r + 1; uu = cst - v; }   // tight vs post-update v
        if (i0 > 0){
          if (m1 < m2){ r = i0 - 1; continue; }    // steal: reprocess immediately
          freemask |= (1u << (i0 - 1));            // tie: occupant to next pass
        }
        break;
      }
    }
    freemask |= cur;   // guard overflow leftovers -> SAP
  }
  // --- SAP for remaining free rows (r10-validated body; uu0 = U[r] feasible)
  int way = 0;
  for (int i = 1; i <= 32; ++i){
    if (!((freemask >> (i-1)) & 1u)) continue;
    float minv = 1e30f;
    int used = (l < 32) ? 0 : 1;
    way = 0;
    float uu0 = U[i-1];
    int j0 = 0;
    float u0 = uu0;
    float cst = CL[(i-1)*32 + lc];
    for (int guard = 0; guard < 64; ++guard){
      float cur2 = cst - u0 - v;
      if (!used && cur2 < minv){ minv = cur2; way = j0; }
      float mval = used ? 1e30f : minv;
      float dmin = wave_min32(mval);
      unsigned long long b = __ballot(mval == dmin);
      int j1 = __builtin_ctzll(b) + 1;
      int pn = __builtin_amdgcn_readlane(p, j1-1);
      int i0n = (pn > 0) ? pn : 1;
      float cstn = CL[(i0n-1)*32 + lc];
      if (used){ uu += dmin; v -= dmin; } else { minv -= dmin; }
      uu0 += dmin;
      j0 = j1;
      if (pn == 0) break;
      if (l == j1-1) used = 1;
      u0 = __int_as_float(__builtin_amdgcn_readlane(__float_as_int(uu), j1-1));
      cst = cstn;
    }
    for (int guard = 0; guard < 40 && j0 != 0; ++guard){
      int jw = __builtin_amdgcn_readlane(way, j0-1);
      int pp_; float pu;
      if (jw == 0){ pp_ = i; pu = uu0; }
      else {
        pp_ = __builtin_amdgcn_readlane(p, jw-1);
        pu = __int_as_float(__builtin_amdgcn_readlane(__float_as_int(uu), jw-1));
      }
      if (l == j0-1){ p = pp_; uu = pu; }
      j0 = jw;
    }
  }
  float csum = 0.f;
  if (l < 32) csum = CL[(p-1)*32 + l];
  for (int k = 1; k < 64; k <<= 1) csum += __shfl_xor(csum, k);
  float lex = 0.f;
  if (l < 32){
    float pv = psin[l];
    pv = fminf(fmaxf(pv, 1e-6f), 1.f - 1e-6f);
    lex = -logf(pv);
  }
  for (int k = 1; k < 64; k <<= 1) lex += __shfl_xor(lex, k);
  if (l == 0)
    out[0] = csum/32.f + 100.f*(lex/32.f) + 100.f*LN2;
}

extern "C" void kernel_launch(void* const* d_in, const int* in_sizes, int n_in,
                              void* d_out, int out_size, void* d_ws, size_t ws_size,
                              hipStream_t stream)
{
  (void)in_sizes; (void)n_in; (void)out_size;
  const float* pe  = (const float*)d_in[0];
  const float* ps  = (const float*)d_in[1];
  const int*   gt  = (const int*)  d_in[2];
  const float* wgt = (const float*)d_in[3];
  float* ws  = (float*)d_ws;
  float* out = (float*)d_out;
  int nb = 1042;
  if (ws_size < ((size_t)PART_OFF + (size_t)1024*nb)*4u) nb = 521;
  hipLaunchKernelGGL(k1_prep,   dim3(1),    dim3(256), 0, stream, pe, gt, ws);
  hipLaunchKernelGGL(k2_main,   dim3(nb),   dim3(256), 0, stream, wgt, ws, gt,
                     ws + PART_OFF, ws, nb);
  hipLaunchKernelGGL(k3_reduce, dim3(1024), dim3(64),  0, stream,
                     ws + PART_OFF, ws, nb);
  hipLaunchKernelGGL(k4_final,  dim3(1),    dim3(64),  0, stream, ps, ws, out);
}

// Round 13
// 107.896 us; speedup vs baseline: 1.3611x; 1.3611x over previous
//
#include <hip/hip_runtime.h>
#include <hip/hip_bf16.h>

#define NCLS   100000
#define FEAT   192
#define F4     48
#define TILE   32
#define NT2    3125        // NCLS/TILE exact

// workspace layout (float offsets)
#define XN_OFF   0
#define CM_OFF   6144
#define SM_OFF   6176
#define TH_OFF   6208
#define MM_OFF   6240
#define RG_OFF   6272
#define LV_OFF   6304
#define TGT_OFF  6336
#define CMAT_OFF 7360
#define XNH_OFF  8384      // 6144 ushort (bf16 hi of xn) = 3072 float slots
#define XNL_OFF  11456     // 6144 ushort (bf16 lo)
#define PART_OFF 14528

#define L2E30 43.2808512266689f
#define LN2   0.69314718055994531f

typedef __attribute__((ext_vector_type(8))) short bf16x8;
typedef __attribute__((ext_vector_type(4))) float f32x4;

__device__ __forceinline__ float dot4(float4 a, float4 b){
  return fmaf(a.x,b.x, fmaf(a.y,b.y, fmaf(a.z,b.z, a.w*b.w)));
}
__device__ __forceinline__ unsigned short bf_bits(__hip_bfloat16 h){
  return *reinterpret_cast<unsigned short*>(&h);
}
__device__ __forceinline__ float bf_up(short s){
  return __int_as_float(((int)(unsigned short)s) << 16);
}

// ---------------- K1: prep (params, lv, xn -> bf16 hi/lo split) ----------------
__global__ __launch_bounds__(256) void k1_prep(const float* __restrict__ pe,
                                               const int* __restrict__ gt,
                                               float* __restrict__ ws)
{
  __shared__ float4 PE4[1536];
  __shared__ float INVN[32];
  const int tid = threadIdx.x;
  const float4* pe4 = (const float4*)pe;
  for (int i = tid; i < 1536; i += 256) PE4[i] = pe4[i];
  __syncthreads();

  const int m   = tid >> 3;
  const int sub = tid & 7;
  float ssq = 0.f;
  for (int j = 0; j < 6; ++j){ float4 v = PE4[m*F4 + sub + 8*j]; ssq += dot4(v,v); }
  ssq += __shfl_xor(ssq,1); ssq += __shfl_xor(ssq,2); ssq += __shfl_xor(ssq,4);
  float nrm = sqrtf(ssq);
  if (sub == 0){
    INVN[m] = 1.f / fmaxf(nrm, 1e-12f);
    float nc = fminf(fmaxf(nrm, 10.f), 110.f);
    float mi = fmaf(0.01f, nc, 100.f/nc);
    const float pi = 3.14159265358979323846f;
    ws[CM_OFF+m] = cosf(mi);
    ws[SM_OFF+m] = sinf(mi);
    ws[TH_OFF+m] = cosf(pi - mi);
    ws[MM_OFF+m] = sinf(pi - mi)*mi;
    float dr = nc - 60.f;
    ws[RG_OFF+m] = 0.07f*dr*dr;              // GAMMA*LMBDA*0.01 = 0.07
  }
  if (tid < 32) ws[LV_OFF+tid] = (float)gt[tid];
  __syncthreads();

  unsigned short* xh = (unsigned short*)(ws + XNH_OFF);
  unsigned short* xl = (unsigned short*)(ws + XNL_OFF);
  for (int i = tid; i < 6144; i += 256){
    float v = ((float*)PE4)[i] * INVN[i/FEAT];
    ws[XN_OFF+i] = v;
    __hip_bfloat16 hb = __float2bfloat16(v);
    float hf = __bfloat162float(hb);
    __hip_bfloat16 lb = __float2bfloat16(v - hf);
    xh[i] = bf_bits(hb);
    xl[i] = bf_bits(lb);
  }
}

// ---------------- K2: MFMA split-bf16 GEMM + transform + online MAX (r11) ----------------
__global__ __launch_bounds__(256, 4) void k2_main(const float* __restrict__ wgt,
                                                  const float* __restrict__ wsr,
                                                  const int* __restrict__ gt,
                                                  float* __restrict__ part,
                                                  float* __restrict__ wsw,
                                                  int nb)
{
  __shared__ __align__(16) short WH[TILE*FEAT];   // 12KB, swizzled bf16-hi
  __shared__ __align__(16) short WL[TILE*FEAT];   // 12KB, swizzled bf16-lo
  __shared__ float4 OBS[TILE*8];                  // 4KB
  __shared__ float4 OSS[TILE*8];                  // 4KB
  __shared__ float  NRM[TILE];
  __shared__ float4 PRM[32];                      // {cm, sm, th, mm} per m

  const int tid  = threadIdx.x;
  const int lane = tid & 63;
  const int wv   = tid >> 6;
  const int clsg = wv & 1;          // cls 16-group
  const int mh   = wv >> 1;         // m half
  const float4* gw4 = (const float4*)wgt;

  if (tid < 32)
    PRM[tid] = make_float4(wsr[CM_OFF+tid], wsr[SM_OFF+tid],
                           wsr[TH_OFF+tid], wsr[MM_OFF+tid]);

  const unsigned short* xh = (const unsigned short*)(wsr + XNH_OFF);
  const unsigned short* xl = (const unsigned short*)(wsr + XNL_OFF);
  const int arow = mh*16 + (lane & 15);     // m row of A-frag
  const int acol = (lane >> 4) * 8;         // k sub-offset of A-frag
  const int bcls = clsg*16 + (lane & 15);   // cls column of B-frag
  const int bxor = (bcls & 7) << 4;

  const int s_acc = tid & 31;
  const int mgr   = tid >> 5;
  const int gt_s  = gt[s_acc];
  const float lvs = (float)gt_s;
  float mx[4];
#pragma unroll
  for (int qi = 0; qi < 4; ++qi) mx[qi] = -1e30f;

  for (int t = blockIdx.x; t < NT2; t += nb){
    const int c0 = t*TILE;
#pragma unroll
    for (int r = 0; r < 6; ++r){
      int f = r*256 + tid;
      float4 w4 = gw4[(long)t*1536 + f];
      int cls = f / F4;
      int k4  = f - cls*F4;
      float vals[4] = { w4.x, w4.y, w4.z, w4.w };
      unsigned short hb4[4], lb4[4];
#pragma unroll
      for (int e = 0; e < 4; ++e){
        __hip_bfloat16 hb = __float2bfloat16(vals[e]);
        float hf = __bfloat162float(hb);
        __hip_bfloat16 lb = __float2bfloat16(vals[e] - hf);
        hb4[e] = bf_bits(hb); lb4[e] = bf_bits(lb);
      }
      int phys = (cls*384 + k4*8) ^ ((cls & 7) << 4);
      *(ushort4*)((char*)WH + phys) = make_ushort4(hb4[0],hb4[1],hb4[2],hb4[3]);
      *(ushort4*)((char*)WL + phys) = make_ushort4(lb4[0],lb4[1],lb4[2],lb4[3]);
    }
    __syncthreads();                        // barC: tile staged
    {
      int cls = tid >> 3, seg = tid & 7;
      float nsq = 0.f;
#pragma unroll
      for (int j = 0; j < 3; ++j){
        int phys = (cls*384 + seg*48 + j*16) ^ ((cls & 7) << 4);
        bf16x8 hh = *(const bf16x8*)((char*)WH + phys);
        bf16x8 ll = *(const bf16x8*)((char*)WL + phys);
#pragma unroll
        for (int e = 0; e < 8; ++e){
          float wv_ = bf_up(hh[e]) + bf_up(ll[e]);
          nsq = fmaf(wv_, wv_, nsq);
        }
      }
      nsq += __shfl_xor(nsq,1); nsq += __shfl_xor(nsq,2); nsq += __shfl_xor(nsq,4);
      if (seg == 0) NRM[cls] = rsqrtf(fmaxf(nsq, 1e-24f));
    }
    f32x4 acc = {0.f, 0.f, 0.f, 0.f};
#pragma unroll
    for (int ks = 0; ks < 6; ++ks){
      int boff = (bcls*384 + ks*64 + (lane>>4)*16) ^ bxor;
      bf16x8 bh = *(const bf16x8*)((char*)WH + boff);
      bf16x8 bl = *(const bf16x8*)((char*)WL + boff);
      int aoff = arow*FEAT + ks*32 + acol;
      bf16x8 ah = *(const bf16x8*)(xh + aoff);
      bf16x8 al = *(const bf16x8*)(xl + aoff);
      acc = __builtin_amdgcn_mfma_f32_16x16x32_bf16(ah, bh, acc, 0, 0, 0);
      acc = __builtin_amdgcn_mfma_f32_16x16x32_bf16(al, bh, acc, 0, 0, 0);
      acc = __builtin_amdgcn_mfma_f32_16x16x32_bf16(ah, bl, acc, 0, 0, 0);
    }
    __syncthreads();                        // barA: MFMA done, NRM visible
    {
      float invn = NRM[bcls];
      float ob[4], os[4];
#pragma unroll
      for (int r = 0; r < 4; ++r){
        float c = acc[r] * invn;
        float4 pr = PRM[mh*16 + (lane>>4)*4 + r];
        float sine = sqrtf(fminf(fmaxf(1.f - c*c, 0.f), 1.f));
        float phi = c*pr.x - sine*pr.y;
        phi = (c > pr.z) ? phi : (c - pr.w);
        ob[r] = L2E30 * c;
        os[r] = L2E30 * (phi - c);
      }
      int mgw = mh*4 + (lane>>4);
      int slot = bcls*8 + (mgw ^ (bcls & 7));
      OBS[slot] = make_float4(ob[0],ob[1],ob[2],ob[3]);
      OSS[slot] = make_float4(os[0],os[1],os[2],os[3]);
    }
    __syncthreads();                        // barB: OBS/OSS visible
    {
      int rel = gt_s - c0;
      if ((unsigned)rel < (unsigned)TILE){
        int slot = rel*8 + (mgr ^ (rel & 7));
        float4 ob = OBS[slot];
        float4 os = OSS[slot];
        wsw[TGT_OFF + s_acc*32 + 4*mgr + 0] = fmaf(lvs, os.x, ob.x);
        wsw[TGT_OFF + s_acc*32 + 4*mgr + 1] = fmaf(lvs, os.y, ob.y);
        wsw[TGT_OFF + s_acc*32 + 4*mgr + 2] = fmaf(lvs, os.z, ob.z);
        wsw[TGT_OFF + s_acc*32 + 4*mgr + 3] = fmaf(lvs, os.w, ob.w);
      }
    }
#pragma unroll 8
    for (int ci = 0; ci < TILE; ++ci){
      int slot = ci*8 + (mgr ^ (ci & 7));
      float4 ob = OBS[slot];
      float4 os = OSS[slot];
      mx[0] = fmaxf(mx[0], fmaf(lvs, os.x, ob.x));
      mx[1] = fmaxf(mx[1], fmaf(lvs, os.y, ob.y));
      mx[2] = fmaxf(mx[2], fmaf(lvs, os.z, ob.z));
      mx[3] = fmaxf(mx[3], fmaf(lvs, os.w, ob.w));
    }
  }
#pragma unroll
  for (int qi = 0; qi < 4; ++qi){
    int pp = s_acc*32 + 4*mgr + qi;
    part[(long)pp*nb + blockIdx.x] = mx[qi];
  }
}

// ---------------- K3: combine partial maxes -> cost matrix ----------------
__global__ __launch_bounds__(64) void k3_reduce(const float* part, float* ws, int nb)
{
  const int p = blockIdx.x;
  const int l = threadIdx.x;
  float M = -1e30f;
  for (int base = l; base < nb; base += 64)
    M = fmaxf(M, part[(long)p*nb + base]);
  for (int k = 1; k < 64; k <<= 1)
    M = fmaxf(M, __shfl_xor(M, k));
  if (l == 0)
    ws[CMAT_OFF + p] = LN2*(M - ws[TGT_OFF + p]) + ws[RG_OFF + (p & 31)];
}

// ---------------- K4: JV init (greedy) + SAP — r11-exact (measured 63us) ----------------
__device__ __forceinline__ float wave_min32(float x){
  float r = x;
#define DPPSTEP(ctrl) { int t_ = __builtin_amdgcn_update_dpp(__float_as_int(r), __float_as_int(r), (ctrl), 0xf, 0xf, false); r = fminf(r, __int_as_float(t_)); }
  DPPSTEP(0x111)
  DPPSTEP(0x112)
  DPPSTEP(0x114)
  DPPSTEP(0x118)
  DPPSTEP(0x142)
#undef DPPSTEP
  return __int_as_float(__builtin_amdgcn_readlane(__float_as_int(r), 31));
}

__global__ __launch_bounds__(64) void k4_final(const float* __restrict__ psin,
                                               const float* __restrict__ wsr,
                                               float* __restrict__ out)
{
  __shared__ float CL[1024];
  __shared__ float U[32];
  const int l = threadIdx.x;
  const int lc = l & 31;
  for (int i = l; i < 1024; i += 64) CL[i] = wsr[CMAT_OFF + i];
  __syncthreads();

  for (int i = 0; i < 32; ++i){
    float val = (l < 32) ? CL[i*32 + lc] : 1e30f;
    float mn = wave_min32(val);
    if (l == 0) U[i] = mn;
  }
  __syncthreads();
  float v = 1e30f;
#pragma unroll 8
  for (int i = 0; i < 32; ++i) v = fminf(v, CL[i*32 + lc] - U[i]);
  int p = 0;
  float uu = 0.f;
  unsigned rowmask = 0;
  for (int i = 0; i < 32; ++i){
    float rc = CL[i*32 + lc] - U[i] - v;
    bool z = (l < 32) && (p == 0) && (rc == 0.0f);
    unsigned long long b = __ballot(z);
    if (b){
      int j = __builtin_ctzll(b);
      if (l == j){ p = i + 1; uu = U[i]; }
      rowmask |= (1u << i);
    }
  }
  int way = 0;
  for (int i = 1; i <= 32; ++i){
    if ((rowmask >> (i-1)) & 1u) continue;
    float minv = 1e30f;
    int used = (l < 32) ? 0 : 1;
    way = 0;
    float uu0 = U[i-1];
    int j0 = 0;
    float u0 = uu0;
    float cst = CL[(i-1)*32 + lc];
    for (int guard = 0; guard < 64; ++guard){
      float cur = cst - u0 - v;
      if (!used && cur < minv){ minv = cur; way = j0; }
      float mval = used ? 1e30f : minv;
      float dmin = wave_min32(mval);
      unsigned long long b = __ballot(mval == dmin);
      int j1 = __builtin_ctzll(b) + 1;
      int pn = __builtin_amdgcn_readlane(p, j1-1);
      int i0n = (pn > 0) ? pn : 1;
      float cstn = CL[(i0n-1)*32 + lc];
      if (used){ uu += dmin; v -= dmin; } else { minv -= dmin; }
      uu0 += dmin;
      j0 = j1;
      if (pn == 0) break;
      if (l == j1-1) used = 1;
      u0 = __int_as_float(__builtin_amdgcn_readlane(__float_as_int(uu), j1-1));
      cst = cstn;
    }
    for (int guard = 0; guard < 40 && j0 != 0; ++guard){
      int jw = __builtin_amdgcn_readlane(way, j0-1);
      int pp_; float pu;
      if (jw == 0){ pp_ = i; pu = uu0; }
      else {
        pp_ = __builtin_amdgcn_readlane(p, jw-1);
        pu = __int_as_float(__builtin_amdgcn_readlane(__float_as_int(uu), jw-1));
      }
      if (l == j0-1){ p = pp_; uu = pu; }
      j0 = jw;
    }
  }
  float csum = 0.f;
  if (l < 32) csum = CL[(p-1)*32 + l];
  for (int k = 1; k < 64; k <<= 1) csum += __shfl_xor(csum, k);
  float lex = 0.f;
  if (l < 32){
    float pv = psin[l];
    pv = fminf(fmaxf(pv, 1e-6f), 1.f - 1e-6f);
    lex = -logf(pv);
  }
  for (int k = 1; k < 64; k <<= 1) lex += __shfl_xor(lex, k);
  if (l == 0)
    out[0] = csum/32.f + 100.f*(lex/32.f) + 100.f*LN2;
}

extern "C" void kernel_launch(void* const* d_in, const int* in_sizes, int n_in,
                              void* d_out, int out_size, void* d_ws, size_t ws_size,
                              hipStream_t stream)
{
  (void)in_sizes; (void)n_in; (void)out_size;
  const float* pe  = (const float*)d_in[0];
  const float* ps  = (const float*)d_in[1];
  const int*   gt  = (const int*)  d_in[2];
  const float* wgt = (const float*)d_in[3];
  float* ws  = (float*)d_ws;
  float* out = (float*)d_out;
  // nb=1024: exactly 4 resident blocks/CU (33KB LDS) on all 256 CUs — no
  // serialized 5th block (nb=1042 left 18 CUs running a 2x straggler round).
  int nb = 1024;
  if (ws_size < ((size_t)PART_OFF + (size_t)1024*nb)*4u) nb = 512;
  hipLaunchKernelGGL(k1_prep,   dim3(1),    dim3(256), 0, stream, pe, gt, ws);
  hipLaunchKernelGGL(k2_main,   dim3(nb),   dim3(256), 0, stream, wgt, ws, gt,
                     ws + PART_OFF, ws, nb);
  hipLaunchKernelGGL(k3_reduce, dim3(1024), dim3(64),  0, stream,
                     ws + PART_OFF, ws, nb);
  hipLaunchKernelGGL(k4_final,  dim3(1),    dim3(64),  0, stream, ps, ws, out);
}